// Round 10
// baseline (494.882 us; speedup 1.0000x reference)
//
#include <hip/hip_runtime.h>
#include <cstddef>

#define NPTS 32768
#define DDIM 128
#define KCB  1024

typedef __attribute__((ext_vector_type(8))) short short8;  // 8 bf16 (4 VGPRs)
typedef __attribute__((ext_vector_type(4))) float f32x4;

// ---------- numeric helpers ----------

__device__ __forceinline__ float hw_exp2(float x) {
#if __has_builtin(__builtin_amdgcn_exp2f)
  return __builtin_amdgcn_exp2f(x);
#else
  return exp2f(x);
#endif
}

__device__ __forceinline__ void atomic_add_f64(double* p, double v) {
  __hip_atomic_fetch_add(p, v, __ATOMIC_RELAXED, __HIP_MEMORY_SCOPE_AGENT);
}

// bf16 round-to-nearest-even of a finite f32 (bit trick; no inf/nan here)
__device__ __forceinline__ unsigned short bf16_rne(float v) {
  unsigned u = __float_as_uint(v);
  unsigned r = u + 0x7FFFu + ((u >> 16) & 1u);
  return (unsigned short)(r >> 16);
}
__device__ __forceinline__ float bf16_tof(unsigned short h) {
  return __uint_as_float((unsigned)h << 16);
}

// correctly-rounded f32 division via 2-FMA Markstein refinement (rc = RN(1/c));
// bit-identical to IEEE '/' given correctly-rounded rc.
__device__ __forceinline__ float div_mark(float x, float c, float rc) {
  float q0 = x * rc;
  float r  = fmaf(-c, q0, x);
  return fmaf(r, rc, q0);
}

// E = exp(-dc/eps) with f64 range, rel err ~8e-8 (errors average out in the
// Sinkhorn row/col sums; NOT used for the final argmax score).
__device__ __forceinline__ double sweep_E(float cv, float middle, float amp, float rc_amp) {
  float d  = div_mark(1.0f - cv, 0.2f, 1.0f / 0.2f);
  float dc = div_mark(d - middle, amp, rc_amp);
  double xl2 = (double)dc * (-288.53900817779268);  // 200*log2(e)
  double kd  = rint(xl2);
  float  fr  = (float)(xl2 - kd);
  float  m   = hw_exp2(fr);
  long long bits = ((long long)(1023 + (int)kd)) << 52;
  return (double)m * __longlong_as_double(bits);
}

// f32 per-element ops matching jnp, for the exact-recheck score exponent
__device__ __forceinline__ double score_exponent(float cv, float middle, float amplitude) {
  float d  = (1.0f - cv) / 0.2f;
  float dc = (d - middle) / amplitude;
  return (double)dc * (-(1.0 / 0.005));
}

// order-preserving f32 <-> u32 encode for atomic min/max
__device__ __forceinline__ unsigned enc_f32(float f) {
  unsigned u = __float_as_uint(f);
  return (u & 0x80000000u) ? ~u : (u | 0x80000000u);
}
__device__ __forceinline__ float dec_f32(unsigned e) {
  unsigned u = (e & 0x80000000u) ? (e & 0x7FFFFFFFu) : ~e;
  return __uint_as_float(u);
}

// async global->LDS 16B: per-lane gptr, WAVE-UNIFORM lds base, lane lands at +lane*16
#if __has_builtin(__builtin_amdgcn_global_load_lds)
#define HAVE_ASYNC_LDS 1
typedef __attribute__((address_space(3))) unsigned int lds_u32_t;
typedef const __attribute__((address_space(1))) unsigned int glb_u32_t;
__device__ __forceinline__ void async_ld16(const void* g, void* l) {
  __builtin_amdgcn_global_load_lds((glb_u32_t*)g, (lds_u32_t*)l, 16, 0, 0);
}
#else
#define HAVE_ASYNC_LDS 0
#endif

// ---------- kernels ----------

__global__ __launch_bounds__(1024) void vq_init_kernel(double* __restrict__ u123,
                                                       double* __restrict__ loss_part,
                                                       unsigned* __restrict__ maxenc,
                                                       unsigned* __restrict__ minenc) {
  int t = threadIdx.x;
  for (int i = t; i < 3 * KCB; i += 1024) u123[i] = 0.0;
  loss_part[t] = 0.0;
  if (t == 0) {
    *maxenc = 0u;
    *minenc = 0xFFFFFFFFu;
  }
}

// L2-normalize rows, emit f32 (used post-GEMM for the precise recheck path)
__global__ __launch_bounds__(128) void vq_normalize_rows(const float* __restrict__ in,
                                                         float* __restrict__ out) {
  int row = blockIdx.x;
  int t = threadIdx.x;
  float v = in[(size_t)row * DDIM + t];
  float s = v * v;
#pragma unroll
  for (int off = 32; off; off >>= 1) s += __shfl_down(s, off, 64);
  __shared__ float red[2];
  if ((t & 63) == 0) red[t >> 6] = s;
  __syncthreads();
  float norm = sqrtf(red[0] + red[1]);
  out[(size_t)row * DDIM + t] = v / fmaxf(norm, 1e-12f);
}

// L2-normalize rows, emit split bf16 planes: v = hi + lo + O(2^-18 v)
__global__ __launch_bounds__(128) void vq_normalize_split(const float* __restrict__ in,
                                                          unsigned short* __restrict__ oh,
                                                          unsigned short* __restrict__ ol) {
  int row = blockIdx.x;
  int t = threadIdx.x;
  float v = in[(size_t)row * DDIM + t];
  float s = v * v;
#pragma unroll
  for (int off = 32; off; off >>= 1) s += __shfl_down(s, off, 64);
  __shared__ float red[2];
  if ((t & 63) == 0) red[t >> 6] = s;
  __syncthreads();
  float norm = sqrtf(red[0] + red[1]);
  float xnv = v / fmaxf(norm, 1e-12f);
  unsigned short h = bf16_rne(xnv);
  float fh = bf16_tof(h);
  unsigned short l = bf16_rne(xnv - fh);  // v - fh exact in f32
  size_t idx = (size_t)row * DDIM + t;
  oh[idx] = h;
  ol[idx] = l;
}

// ---- MFMA GEMM, LDS double-buffered + async staging: cos = A·B^T, 2-way bf16 split.
// Per K-chunk: ds_read(cur) FIRST (no pending vmcnt -> no forced wait), then
// issue async stage(next) which overlaps the MFMA burst; the end-barrier's
// vmcnt drain is covered by compute. m97-style single-barrier K-loop.
#define LROWS 32

__global__ __launch_bounds__(256) void vq_gemm_mfma(const unsigned short* __restrict__ Ah,
                                                    const unsigned short* __restrict__ Al,
                                                    const unsigned short* __restrict__ Bh,
                                                    const unsigned short* __restrict__ Bl,
                                                    float* __restrict__ Cm,
                                                    unsigned* __restrict__ maxenc,
                                                    unsigned* __restrict__ minenc) {
  __shared__ unsigned short Ahs[2][128 * LROWS], Als[2][128 * LROWS];  // 8KB each
  __shared__ unsigned short Bhs[2][128 * LROWS], Bls[2][128 * LROWS];  // total 64KB
  __shared__ float redmx[4], redmn[4];
  int tid = threadIdx.x;
  int lane = tid & 63, wv = tid >> 6;
  int wr = wv >> 1, wc = wv & 1;
  int n0 = blockIdx.x * 128;  // x = row-block: consecutive blocks share B strip in L2
  int c0 = blockIdx.y * 128;
  int fr = lane & 15;
  int kq = (lane >> 4) * 8;
  f32x4 acc[4][4] = {};  // [rt][ct]

  auto stage = [&](int ks, int b) {
    int kc = ks * 32;
#pragma unroll
    for (int l = 0; l < 2; ++l) {
      int idx = tid + l * 256;       // 0..511 16B-chunks; lane-linear within wave
      int row = idx >> 2;            // 0..127
      int sub = idx & 3;             // 16B chunk within the 32-k window
      size_t ga = (size_t)(n0 + row) * DDIM + kc + sub * 8;
      size_t gb = (size_t)(c0 + row) * DDIM + kc + sub * 8;
#if HAVE_ASYNC_LDS
      int wbase = (l * 256 + wv * 64) * 8;  // shorts; wave-uniform
      async_ld16(Ah + ga, &Ahs[b][wbase]);
      async_ld16(Al + ga, &Als[b][wbase]);
      async_ld16(Bh + gb, &Bhs[b][wbase]);
      async_ld16(Bl + gb, &Bls[b][wbase]);
#else
      int lo = idx * 8;
      *(short8*)&Ahs[b][lo] = *(const short8*)(Ah + ga);
      *(short8*)&Als[b][lo] = *(const short8*)(Al + ga);
      *(short8*)&Bhs[b][lo] = *(const short8*)(Bh + gb);
      *(short8*)&Bls[b][lo] = *(const short8*)(Bl + gb);
#endif
    }
  };

  stage(0, 0);
  __syncthreads();  // drains vmcnt: buf0 staged

#pragma unroll
  for (int ks = 0; ks < 4; ++ks) {
    int cur = ks & 1;
    // 1) LDS -> registers for this chunk (only lgkmcnt involved)
    short8 ah[4], al[4], bh[4], bl[4];
#pragma unroll
    for (int rt = 0; rt < 4; ++rt) {
      int lo = (wr * 64 + rt * 16 + fr) * LROWS + kq;
      ah[rt] = *(const short8*)&Ahs[cur][lo];
      al[rt] = *(const short8*)&Als[cur][lo];
    }
#pragma unroll
    for (int ct = 0; ct < 4; ++ct) {
      int lo = (wc * 64 + ct * 16 + fr) * LROWS + kq;
      bh[ct] = *(const short8*)&Bhs[cur][lo];
      bl[ct] = *(const short8*)&Bls[cur][lo];
    }
    // 2) issue async staging of the next chunk into the other buffer
    if (ks < 3) stage(ks + 1, cur ^ 1);
    // 3) MFMA burst overlaps the in-flight staging
#pragma unroll
    for (int rt = 0; rt < 4; ++rt) {
#pragma unroll
      for (int ct = 0; ct < 4; ++ct) {
        acc[rt][ct] = __builtin_amdgcn_mfma_f32_16x16x32_bf16(ah[rt], bh[ct], acc[rt][ct], 0, 0, 0);
        acc[rt][ct] = __builtin_amdgcn_mfma_f32_16x16x32_bf16(ah[rt], bl[ct], acc[rt][ct], 0, 0, 0);
        acc[rt][ct] = __builtin_amdgcn_mfma_f32_16x16x32_bf16(al[rt], bh[ct], acc[rt][ct], 0, 0, 0);
        acc[rt][ct] = __builtin_amdgcn_mfma_f32_16x16x32_bf16(al[rt], bl[ct], acc[rt][ct], 0, 0, 0);
      }
    }
    // 4) barrier: next-chunk staging complete; all reads of cur done
    __syncthreads();
  }

  float mx = -3.402823466e38f, mn = 3.402823466e38f;
  int orow = (lane >> 4) * 4, ocol = lane & 15;
  int rn0 = n0 + wr * 64, rc0 = c0 + wc * 64;
#pragma unroll
  for (int rt = 0; rt < 4; ++rt) {
#pragma unroll
    for (int ct = 0; ct < 4; ++ct) {
#pragma unroll
      for (int r = 0; r < 4; ++r) {
        float v = acc[rt][ct][r];
        mx = fmaxf(mx, v);
        mn = fminf(mn, v);
        Cm[(size_t)(rn0 + rt * 16 + orow + r) * KCB + (rc0 + ct * 16 + ocol)] = v;
      }
    }
  }
#pragma unroll
  for (int off = 32; off; off >>= 1) {
    mx = fmaxf(mx, __shfl_down(mx, off, 64));
    mn = fminf(mn, __shfl_down(mn, off, 64));
  }
  if (lane == 0) { redmx[wv] = mx; redmn[wv] = mn; }
  __syncthreads();
  if (tid == 0) {
    mx = fmaxf(fmaxf(redmx[0], redmx[1]), fmaxf(redmx[2], redmx[3]));
    mn = fminf(fminf(redmn[0], redmn[1]), fminf(redmn[2], redmn[3]));
    atomicMax(maxenc, enc_f32(mx));
    atomicMin(minenc, enc_f32(mn));
  }
}

// scal: [0]=middle, [1]=amplitude, [2]=rc_amp
__global__ void vq_scalarize(const unsigned* __restrict__ maxenc,
                             const unsigned* __restrict__ minenc,
                             float* __restrict__ scal) {
  float cosmax = dec_f32(*maxenc);
  float cosmin = dec_f32(*minenc);
  float mx_d = (1.0f - cosmin) / 0.2f;
  float mn_d = (1.0f - cosmax) / 0.2f;
  float middle = (mx_d + mn_d) / 2.0f;
  float amplitude = fmaxf(mx_d - middle + 1e-5f, 1e-5f);
  scal[0] = middle;
  scal[1] = amplitude;
  scal[2] = 1.0f / amplitude;
}

// ---- Sinkhorn sweep: wave-per-row, zero per-row barriers, depth-2 prefetch ----
#define SROWS 32
#define SRPW  8

__global__ __launch_bounds__(256) void vq_sweep(const float* __restrict__ Cm,
                                                const float* __restrict__ scal,
                                                const double* __restrict__ Rvec,
                                                const double* __restrict__ alpha_p,
                                                double* __restrict__ u_out) {
  int t = threadIdx.x;
  int lane = t & 63, wv = t >> 6;
  int n0 = blockIdx.x * SROWS + wv * SRPW;
  float middle = scal[0], amp = scal[1], rc = scal[2];
  bool hasR = (Rvec != nullptr);
  double Rreg[16];
  double ainv = 0.0;
  if (hasR) {
#pragma unroll
    for (int c = 0; c < 4; ++c)
#pragma unroll
      for (int e = 0; e < 4; ++e) Rreg[c * 4 + e] = Rvec[c * 256 + lane * 4 + e];
    ainv = alpha_p[0] * 32768.0;
  }
  double up[16] = {};
  float4 buf[2][4];
  {
    const float4* r0 = (const float4*)(Cm + (size_t)n0 * KCB);
    const float4* r1 = (const float4*)(Cm + (size_t)(n0 + 1) * KCB);
#pragma unroll
    for (int c = 0; c < 4; ++c) { buf[0][c] = r0[c * 64 + lane]; buf[1][c] = r1[c * 64 + lane]; }
  }
#pragma unroll 1
  for (int r = 0; r < SRPW; ++r) {
    int slot = r & 1;
    double e[16];
#pragma unroll
    for (int c = 0; c < 4; ++c) {
      e[c * 4 + 0] = sweep_E(buf[slot][c].x, middle, amp, rc);
      e[c * 4 + 1] = sweep_E(buf[slot][c].y, middle, amp, rc);
      e[c * 4 + 2] = sweep_E(buf[slot][c].z, middle, amp, rc);
      e[c * 4 + 3] = sweep_E(buf[slot][c].w, middle, amp, rc);
    }
    // reload this slot with row r+2 (clamped; trailing dup loads harmless)
    {
      int rn = (r + 2 < SRPW) ? r + 2 : SRPW - 1;
      const float4* rown = (const float4*)(Cm + (size_t)(n0 + rn) * KCB);
#pragma unroll
      for (int c = 0; c < 4; ++c) buf[slot][c] = rown[c * 64 + lane];
    }
    if (hasR) {
      double s = 0.0;
#pragma unroll
      for (int i = 0; i < 16; ++i) s += e[i] * Rreg[i];
#pragma unroll
      for (int off = 1; off < 64; off <<= 1) s += __shfl_xor(s, off, 64);
      double C = 1.0 / (ainv * s);
#pragma unroll
      for (int i = 0; i < 16; ++i) up[i] += e[i] * C;
    } else {
#pragma unroll
      for (int i = 0; i < 16; ++i) up[i] += e[i];
    }
  }
  __shared__ double su[4][KCB];  // 32 KB
#pragma unroll
  for (int c = 0; c < 4; ++c)
#pragma unroll
    for (int e = 0; e < 4; ++e) su[wv][c * 256 + lane * 4 + e] = up[c * 4 + e];
  __syncthreads();
#pragma unroll
  for (int j = 0; j < 4; ++j) {
    int k = (t + ((blockIdx.x + j) & 3) * 256) & (KCB - 1);
    double v = su[0][k] + su[1][k] + su[2][k] + su[3][k];
    atomic_add_f64(&u_out[k], v);
  }
}

// mode 0: also compute alpha = 1/max(sum u, 1e-5); mode 2: also lnR
__global__ __launch_bounds__(1024) void vq_finalize_u(const double* __restrict__ u,
                                                      double* __restrict__ alpha_p,
                                                      double* __restrict__ R,
                                                      double* __restrict__ lnR,
                                                      int mode) {
  int k = threadIdx.x;
  double uk = u[k];
  __shared__ double red[16];
  __shared__ double s_alpha;
  if (mode == 0) {
    double s = uk;
#pragma unroll
    for (int off = 32; off; off >>= 1) s += __shfl_down(s, off, 64);
    if ((k & 63) == 0) red[k >> 6] = s;
    __syncthreads();
    if (k == 0) {
      double s0 = 0.0;
      for (int w = 0; w < 16; ++w) s0 += red[w];
      double a = 1.0 / fmax(s0, 1e-5);
      s_alpha = a;
      alpha_p[0] = a;
    }
    __syncthreads();
  }
  double alpha = (mode == 0) ? s_alpha : alpha_p[0];
  double r = 1.0 / (alpha * 1024.0 * uk);
  R[k] = r;
  if (mode == 2) lnR[k] = log(r);
}

// ---- final pass: wave-per-row; f32 top-2 argmax with exact-recheck, CE loss ----
#define FRPW 4
#define MARGIN 0.08f
#define LOG2E 1.44269504088896340736f

__global__ __launch_bounds__(256) void vq_final_pass(const float* __restrict__ Cm,
                                                     const float* __restrict__ x,
                                                     const float* __restrict__ cb,
                                                     const float* __restrict__ xn,
                                                     const float* __restrict__ cn,
                                                     const double* __restrict__ lnR,
                                                     const float* __restrict__ scal,
                                                     double* __restrict__ loss_part,
                                                     float* __restrict__ out_xq,
                                                     float* __restrict__ out_idx) {
  int t = threadIdx.x;
  int lane = t & 63, wv = t >> 6;
  int n0 = blockIdx.x * (4 * FRPW) + wv * FRPW;
  float middle = scal[0], amplitude = scal[1], rc_amp = scal[2];
  float lnRf[16];
  double lnRd[16];
#pragma unroll
  for (int c = 0; c < 4; ++c)
#pragma unroll
    for (int e = 0; e < 4; ++e) {
      double v = lnR[c * 256 + lane * 4 + e];
      lnRd[c * 4 + e] = v;
      lnRf[c * 4 + e] = (float)v;
    }

  double loss_loc = 0.0;
  float4 buf[2][4];
  {
    const float4* r0 = (const float4*)(Cm + (size_t)n0 * KCB);
    const float4* r1 = (const float4*)(Cm + (size_t)(n0 + 1) * KCB);
#pragma unroll
    for (int c = 0; c < 4; ++c) { buf[0][c] = r0[c * 64 + lane]; buf[1][c] = r1[c * 64 + lane]; }
  }
#pragma unroll 1
  for (int r = 0; r < FRPW; ++r) {
    int n = n0 + r;
    int slot = r & 1;
    float4 cva[4];
#pragma unroll
    for (int c = 0; c < 4; ++c) cva[c] = buf[slot][c];
    // reload this slot with row r+2 (clamped)
    {
      int rn = (r + 2 < FRPW) ? r + 2 : FRPW - 1;
      const float4* rown = (const float4*)(Cm + (size_t)(n0 + rn) * KCB);
#pragma unroll
      for (int c = 0; c < 4; ++c) buf[slot][c] = rown[c * 64 + lane];
    }

    float lv[16];
    float sv[16];
    float b1 = -3.402823466e38f, b2 = -3.402823466e38f;
    int k1 = 0;
    float lmax = -3.402823466e38f;
#pragma unroll
    for (int c = 0; c < 4; ++c) {
#pragma unroll
      for (int e = 0; e < 4; ++e) {
        float cvv = (e == 0) ? cva[c].x : (e == 1) ? cva[c].y : (e == 2) ? cva[c].z : cva[c].w;
        int k = c * 256 + lane * 4 + e;  // ascending within lane
        float d  = div_mark(1.0f - cvv, 0.2f, 5.0f);
        float dc = div_mark(d - middle, amplitude, rc_amp);
        float s  = fmaf(dc, -200.0f, lnRf[c * 4 + e]);
        sv[c * 4 + e] = s;
        if (s > b1) { b2 = b1; b1 = s; k1 = k; }
        else if (s > b2) b2 = s;
        float l = div_mark(cvv, 0.2f, 5.0f);
        lv[c * 4 + e] = l;
        lmax = fmaxf(lmax, l);
      }
    }
    // butterfly top-2 (tie -> smaller k) + max reduce; all lanes converge
#pragma unroll
    for (int off = 1; off < 64; off <<= 1) {
      float o1 = __shfl_xor(b1, off, 64);
      int ok = __shfl_xor(k1, off, 64);
      float o2 = __shfl_xor(b2, off, 64);
      float om = __shfl_xor(lmax, off, 64);
      float cand2;
      if (o1 > b1 || (o1 == b1 && ok < k1)) { cand2 = fmaxf(b1, o2); b1 = o1; k1 = ok; }
      else cand2 = fmaxf(o1, o2);
      b2 = fmaxf(b2, cand2);
      lmax = fmaxf(lmax, om);
    }
    int bestk = k1;
    if (b1 - b2 < MARGIN) {
      // close call: recheck flagged candidates with exact f32 dot + f64 score
      double pbest = -1.0e308;
      int pk = KCB;
      const float* xr = xn + (size_t)n * DDIM;
      float thr = b1 - MARGIN;
#pragma unroll 1
      for (int i = 0; i < 16; ++i) {
        if (sv[i] >= thr) {
          int k = (i >> 2) * 256 + lane * 4 + (i & 3);
          const float* cr = cn + (size_t)k * DDIM;
          float dot = 0.0f;
          for (int d = 0; d < DDIM; ++d) dot = fmaf(xr[d], cr[d], dot);
          double ps = score_exponent(dot, middle, amplitude) + lnRd[i];
          if (ps > pbest || (ps == pbest && k < pk)) { pbest = ps; pk = k; }
        }
      }
#pragma unroll
      for (int off = 1; off < 64; off <<= 1) {
        double ob = __shfl_xor(pbest, off, 64);
        int ok = __shfl_xor(pk, off, 64);
        if (ob > pbest || (ob == pbest && ok < pk)) { pbest = ob; pk = ok; }
      }
      bestk = pk;
    }
    // sum exp (f32, fused exp2) + extract l[bestk]
    float se = 0.0f;
    float lb = 0.0f;
#pragma unroll
    for (int c = 0; c < 4; ++c) {
#pragma unroll
      for (int e = 0; e < 4; ++e) {
        int k = c * 256 + lane * 4 + e;
        se += hw_exp2((lv[c * 4 + e] - lmax) * LOG2E);
        if (k == bestk) lb = lv[c * 4 + e];
      }
    }
#pragma unroll
    for (int off = 1; off < 64; off <<= 1) {
      se += __shfl_xor(se, off, 64);
      lb += __shfl_xor(lb, off, 64);  // exactly one lane nonzero
    }
    loss_loc += (double)(-(lb - lmax - logf(se)));
    if (lane == 0) out_idx[n] = (float)bestk;
    float2 xv = *(const float2*)&x[(size_t)n * DDIM + lane * 2];
    float2 cbv = *(const float2*)&cb[(size_t)bestk * DDIM + lane * 2];
    float2 o;
    o.x = xv.x + (cbv.x - xv.x);
    o.y = xv.y + (cbv.y - xv.y);
    *(float2*)&out_xq[(size_t)n * DDIM + lane * 2] = o;
  }
  if (lane == 0) atomic_add_f64(&loss_part[(blockIdx.x * 4 + wv) & (KCB - 1)], loss_loc);
}

__global__ __launch_bounds__(1024) void vq_loss_div(const double* __restrict__ lp,
                                                    float* __restrict__ out_loss) {
  int t = threadIdx.x;
  double s = lp[t];
#pragma unroll
  for (int off = 32; off; off >>= 1) s += __shfl_down(s, off, 64);
  __shared__ double red[16];
  if ((t & 63) == 0) red[t >> 6] = s;
  __syncthreads();
  if (t == 0) {
    double tot = 0.0;
    for (int w = 0; w < 16; ++w) tot += red[w];
    out_loss[0] = (float)(tot / 32768.0);
  }
}

// ---------- launch ----------

extern "C" void kernel_launch(void* const* d_in, const int* in_sizes, int n_in,
                              void* d_out, int out_size, void* d_ws, size_t ws_size,
                              hipStream_t stream) {
  const float* x  = (const float*)d_in[0];
  const float* cb = (const float*)d_in[1];
  float* out = (float*)d_out;
  float* out_xq   = out;
  float* out_loss = out + (size_t)NPTS * DDIM;
  float* out_idx  = out + (size_t)NPTS * DDIM + 1;

  // workspace layout (~144.6 MB):
  // [0, 16.5MB): phase 1 = bf16 planes (xh 8M, xl 8M, ch 256K, cl 256K)
  //              phase 2 (post-GEMM) = xn f32 16M, cn f32 512K  (overlay)
  char* w = (char*)d_ws;
  unsigned short* xh = (unsigned short*)w;                         // N*D bf16
  unsigned short* xl = xh + (size_t)NPTS * DDIM;                   // N*D bf16
  unsigned short* ch = xl + (size_t)NPTS * DDIM;                   // K*D bf16
  unsigned short* cl = ch + (size_t)KCB * DDIM;                    // K*D bf16
  float* xn = (float*)w;                                           // N*D f32 (overlay)
  float* cn = xn + (size_t)NPTS * DDIM;                            // K*D f32 (overlay)
  float* cosm = (float*)(w + (size_t)16896 * 1024);                // N*K f32 at +16.5MB
  double* u1  = (double*)(cosm + (size_t)NPTS * KCB);
  double* u2  = u1 + KCB;
  double* u3  = u2 + KCB;
  double* R   = u3 + KCB;
  double* lnR = R + KCB;
  double* loss_part = lnR + KCB;                   // 1024
  double* alpha_p   = loss_part + KCB;
  unsigned* maxenc = (unsigned*)(alpha_p + 1);
  unsigned* minenc = maxenc + 1;
  float* scal = (float*)(minenc + 1);              // middle, amplitude, rc_amp

  vq_init_kernel<<<1, 1024, 0, stream>>>(u1, loss_part, maxenc, minenc);

  // phase 1: split-normalized bf16 planes -> MFMA GEMM (double-buffered async LDS)
  vq_normalize_split<<<NPTS, 128, 0, stream>>>(x, xh, xl);
  vq_normalize_split<<<KCB, 128, 0, stream>>>(cb, ch, cl);
  vq_gemm_mfma<<<dim3(NPTS / 128, KCB / 128), 256, 0, stream>>>(xh, xl, ch, cl, cosm,
                                                                maxenc, minenc);

  // phase 2: f32 normalized copies (overwrite plane region) for the recheck path
  vq_normalize_rows<<<NPTS, 128, 0, stream>>>(x, xn);
  vq_normalize_rows<<<KCB, 128, 0, stream>>>(cb, cn);
  vq_scalarize<<<1, 1, 0, stream>>>(maxenc, minenc, scal);

  // Sinkhorn: u1 -> R1 ; (v1+u2 fused) -> R2 ; (v2+u3 fused) -> R3, lnR3
  vq_sweep<<<NPTS / SROWS, 256, 0, stream>>>(cosm, scal, nullptr, alpha_p, u1);
  vq_finalize_u<<<1, 1024, 0, stream>>>(u1, alpha_p, R, lnR, 0);
  vq_sweep<<<NPTS / SROWS, 256, 0, stream>>>(cosm, scal, R, alpha_p, u2);
  vq_finalize_u<<<1, 1024, 0, stream>>>(u2, alpha_p, R, lnR, 1);
  vq_sweep<<<NPTS / SROWS, 256, 0, stream>>>(cosm, scal, R, alpha_p, u3);
  vq_finalize_u<<<1, 1024, 0, stream>>>(u3, alpha_p, R, lnR, 2);

  vq_final_pass<<<NPTS / (4 * FRPW), 256, 0, stream>>>(cosm, x, cb, xn, cn, lnR, scal,
                                                       loss_part, out_xq, out_idx);
  vq_loss_div<<<1, 1024, 0, stream>>>(loss_part, out_loss);
}

// Round 11
// 318.931 us; speedup vs baseline: 1.5517x; 1.5517x over previous
//
#include <hip/hip_runtime.h>
#include <cstddef>

#define NPTS 32768
#define DDIM 128
#define KCB  1024

typedef __attribute__((ext_vector_type(8))) short short8;  // 8 bf16 (4 VGPRs)
typedef __attribute__((ext_vector_type(4))) float f32x4;

// ---------- numeric helpers ----------

__device__ __forceinline__ float hw_exp2(float x) {
#if __has_builtin(__builtin_amdgcn_exp2f)
  return __builtin_amdgcn_exp2f(x);
#else
  return exp2f(x);
#endif
}

__device__ __forceinline__ void atomic_add_f64(double* p, double v) {
  __hip_atomic_fetch_add(p, v, __ATOMIC_RELAXED, __HIP_MEMORY_SCOPE_AGENT);
}

// bf16 round-to-nearest-even of a finite f32 (bit trick; no inf/nan here)
__device__ __forceinline__ unsigned short bf16_rne(float v) {
  unsigned u = __float_as_uint(v);
  unsigned r = u + 0x7FFFu + ((u >> 16) & 1u);
  return (unsigned short)(r >> 16);
}
__device__ __forceinline__ float bf16_tof(unsigned short h) {
  return __uint_as_float((unsigned)h << 16);
}

// correctly-rounded f32 division via 2-FMA Markstein refinement (rc = RN(1/c));
// bit-identical to IEEE '/' given correctly-rounded rc.
__device__ __forceinline__ float div_mark(float x, float c, float rc) {
  float q0 = x * rc;
  float r  = fmaf(-c, q0, x);
  return fmaf(r, rc, q0);
}

// E = exp(-dc/eps) with f64 range, rel err ~8e-8 (errors average out in the
// Sinkhorn row/col sums; NOT used for the final argmax score).
__device__ __forceinline__ double sweep_E(float cv, float middle, float amp, float rc_amp) {
  float d  = div_mark(1.0f - cv, 0.2f, 1.0f / 0.2f);
  float dc = div_mark(d - middle, amp, rc_amp);
  double xl2 = (double)dc * (-288.53900817779268);  // 200*log2(e)
  double kd  = rint(xl2);
  float  fr  = (float)(xl2 - kd);
  float  m   = hw_exp2(fr);
  long long bits = ((long long)(1023 + (int)kd)) << 52;
  return (double)m * __longlong_as_double(bits);
}

// f32 per-element ops matching jnp, for the exact-recheck score exponent
__device__ __forceinline__ double score_exponent(float cv, float middle, float amplitude) {
  float d  = (1.0f - cv) / 0.2f;
  float dc = (d - middle) / amplitude;
  return (double)dc * (-(1.0 / 0.005));
}

// order-preserving f32 <-> u32 encode for atomic min/max
__device__ __forceinline__ unsigned enc_f32(float f) {
  unsigned u = __float_as_uint(f);
  return (u & 0x80000000u) ? ~u : (u | 0x80000000u);
}
__device__ __forceinline__ float dec_f32(unsigned e) {
  unsigned u = (e & 0x80000000u) ? (e & 0x7FFFFFFFu) : ~e;
  return __uint_as_float(u);
}

// async global->LDS 16B: per-lane gptr, WAVE-UNIFORM lds base, lane lands at +lane*16
#if __has_builtin(__builtin_amdgcn_global_load_lds)
#define HAVE_ASYNC_LDS 1
typedef __attribute__((address_space(3))) unsigned int lds_u32_t;
typedef const __attribute__((address_space(1))) unsigned int glb_u32_t;
__device__ __forceinline__ void async_ld16(const void* g, void* l) {
  __builtin_amdgcn_global_load_lds((glb_u32_t*)g, (lds_u32_t*)l, 16, 0, 0);
}
#else
#define HAVE_ASYNC_LDS 0
#endif

// ---------- kernels ----------

__global__ __launch_bounds__(1024) void vq_init_kernel(double* __restrict__ u123,
                                                       double* __restrict__ loss_part,
                                                       unsigned* __restrict__ maxenc,
                                                       unsigned* __restrict__ minenc) {
  int t = threadIdx.x;
  for (int i = t; i < 3 * KCB; i += 1024) u123[i] = 0.0;
  loss_part[t] = 0.0;
  if (t == 0) {
    *maxenc = 0u;
    *minenc = 0xFFFFFFFFu;
  }
}

// L2-normalize rows, emit f32 (used post-GEMM for the precise recheck path)
__global__ __launch_bounds__(128) void vq_normalize_rows(const float* __restrict__ in,
                                                         float* __restrict__ out) {
  int row = blockIdx.x;
  int t = threadIdx.x;
  float v = in[(size_t)row * DDIM + t];
  float s = v * v;
#pragma unroll
  for (int off = 32; off; off >>= 1) s += __shfl_down(s, off, 64);
  __shared__ float red[2];
  if ((t & 63) == 0) red[t >> 6] = s;
  __syncthreads();
  float norm = sqrtf(red[0] + red[1]);
  out[(size_t)row * DDIM + t] = v / fmaxf(norm, 1e-12f);
}

// L2-normalize rows, emit split bf16 planes: v = hi + lo + O(2^-18 v)
__global__ __launch_bounds__(128) void vq_normalize_split(const float* __restrict__ in,
                                                          unsigned short* __restrict__ oh,
                                                          unsigned short* __restrict__ ol) {
  int row = blockIdx.x;
  int t = threadIdx.x;
  float v = in[(size_t)row * DDIM + t];
  float s = v * v;
#pragma unroll
  for (int off = 32; off; off >>= 1) s += __shfl_down(s, off, 64);
  __shared__ float red[2];
  if ((t & 63) == 0) red[t >> 6] = s;
  __syncthreads();
  float norm = sqrtf(red[0] + red[1]);
  float xnv = v / fmaxf(norm, 1e-12f);
  unsigned short h = bf16_rne(xnv);
  float fh = bf16_tof(h);
  unsigned short l = bf16_rne(xnv - fh);  // v - fh exact in f32
  size_t idx = (size_t)row * DDIM + t;
  oh[idx] = h;
  ol[idx] = l;
}

// ---- MFMA GEMM, LDS double-buffered + async staging: cos = A·B^T, 2-way bf16 split.
// Per K-chunk: ds_read(cur) FIRST (no pending vmcnt -> no forced wait), then
// issue async stage(next) which overlaps the MFMA burst; the end-barrier's
// vmcnt drain is covered by compute.
#define LROWS 32

__global__ __launch_bounds__(256) void vq_gemm_mfma(const unsigned short* __restrict__ Ah,
                                                    const unsigned short* __restrict__ Al,
                                                    const unsigned short* __restrict__ Bh,
                                                    const unsigned short* __restrict__ Bl,
                                                    float* __restrict__ Cm,
                                                    unsigned* __restrict__ maxenc,
                                                    unsigned* __restrict__ minenc) {
  __shared__ unsigned short Ahs[2][128 * LROWS], Als[2][128 * LROWS];  // 8KB each
  __shared__ unsigned short Bhs[2][128 * LROWS], Bls[2][128 * LROWS];  // total 64KB
  __shared__ float redmx[4], redmn[4];
  int tid = threadIdx.x;
  int lane = tid & 63, wv = tid >> 6;
  int wr = wv >> 1, wc = wv & 1;
  int n0 = blockIdx.x * 128;  // x = row-block: consecutive blocks share B strip in L2
  int c0 = blockIdx.y * 128;
  int fr = lane & 15;
  int kq = (lane >> 4) * 8;
  f32x4 acc[4][4] = {};  // [rt][ct]

  auto stage = [&](int ks, int b) {
    int kc = ks * 32;
#pragma unroll
    for (int l = 0; l < 2; ++l) {
      int idx = tid + l * 256;       // 0..511 16B-chunks; lane-linear within wave
      int row = idx >> 2;            // 0..127
      int sub = idx & 3;             // 16B chunk within the 32-k window
      size_t ga = (size_t)(n0 + row) * DDIM + kc + sub * 8;
      size_t gb = (size_t)(c0 + row) * DDIM + kc + sub * 8;
#if HAVE_ASYNC_LDS
      int wbase = (l * 256 + wv * 64) * 8;  // shorts; wave-uniform
      async_ld16(Ah + ga, &Ahs[b][wbase]);
      async_ld16(Al + ga, &Als[b][wbase]);
      async_ld16(Bh + gb, &Bhs[b][wbase]);
      async_ld16(Bl + gb, &Bls[b][wbase]);
#else
      int lo = idx * 8;
      *(short8*)&Ahs[b][lo] = *(const short8*)(Ah + ga);
      *(short8*)&Als[b][lo] = *(const short8*)(Al + ga);
      *(short8*)&Bhs[b][lo] = *(const short8*)(Bh + gb);
      *(short8*)&Bls[b][lo] = *(const short8*)(Bl + gb);
#endif
    }
  };

  stage(0, 0);
  __syncthreads();  // drains vmcnt: buf0 staged

#pragma unroll
  for (int ks = 0; ks < 4; ++ks) {
    int cur = ks & 1;
    // 1) LDS -> registers for this chunk (only lgkmcnt involved)
    short8 ah[4], al[4], bh[4], bl[4];
#pragma unroll
    for (int rt = 0; rt < 4; ++rt) {
      int lo = (wr * 64 + rt * 16 + fr) * LROWS + kq;
      ah[rt] = *(const short8*)&Ahs[cur][lo];
      al[rt] = *(const short8*)&Als[cur][lo];
    }
#pragma unroll
    for (int ct = 0; ct < 4; ++ct) {
      int lo = (wc * 64 + ct * 16 + fr) * LROWS + kq;
      bh[ct] = *(const short8*)&Bhs[cur][lo];
      bl[ct] = *(const short8*)&Bls[cur][lo];
    }
    // 2) issue async staging of the next chunk into the other buffer
    if (ks < 3) stage(ks + 1, cur ^ 1);
    // 3) MFMA burst overlaps the in-flight staging
#pragma unroll
    for (int rt = 0; rt < 4; ++rt) {
#pragma unroll
      for (int ct = 0; ct < 4; ++ct) {
        acc[rt][ct] = __builtin_amdgcn_mfma_f32_16x16x32_bf16(ah[rt], bh[ct], acc[rt][ct], 0, 0, 0);
        acc[rt][ct] = __builtin_amdgcn_mfma_f32_16x16x32_bf16(ah[rt], bl[ct], acc[rt][ct], 0, 0, 0);
        acc[rt][ct] = __builtin_amdgcn_mfma_f32_16x16x32_bf16(al[rt], bh[ct], acc[rt][ct], 0, 0, 0);
        acc[rt][ct] = __builtin_amdgcn_mfma_f32_16x16x32_bf16(al[rt], bl[ct], acc[rt][ct], 0, 0, 0);
      }
    }
    // 4) barrier: next-chunk staging complete; all reads of cur done
    __syncthreads();
  }

  float mx = -3.402823466e38f, mn = 3.402823466e38f;
  int orow = (lane >> 4) * 4, ocol = lane & 15;
  int rn0 = n0 + wr * 64, rc0 = c0 + wc * 64;
#pragma unroll
  for (int rt = 0; rt < 4; ++rt) {
#pragma unroll
    for (int ct = 0; ct < 4; ++ct) {
#pragma unroll
      for (int r = 0; r < 4; ++r) {
        float v = acc[rt][ct][r];
        mx = fmaxf(mx, v);
        mn = fminf(mn, v);
        Cm[(size_t)(rn0 + rt * 16 + orow + r) * KCB + (rc0 + ct * 16 + ocol)] = v;
      }
    }
  }
#pragma unroll
  for (int off = 32; off; off >>= 1) {
    mx = fmaxf(mx, __shfl_down(mx, off, 64));
    mn = fminf(mn, __shfl_down(mn, off, 64));
  }
  if (lane == 0) { redmx[wv] = mx; redmn[wv] = mn; }
  __syncthreads();
  if (tid == 0) {
    mx = fmaxf(fmaxf(redmx[0], redmx[1]), fmaxf(redmx[2], redmx[3]));
    mn = fminf(fminf(redmn[0], redmn[1]), fminf(redmn[2], redmn[3]));
    atomicMax(maxenc, enc_f32(mx));
    atomicMin(minenc, enc_f32(mn));
  }
}

// scal: [0]=middle, [1]=amplitude, [2]=rc_amp
__global__ void vq_scalarize(const unsigned* __restrict__ maxenc,
                             const unsigned* __restrict__ minenc,
                             float* __restrict__ scal) {
  float cosmax = dec_f32(*maxenc);
  float cosmin = dec_f32(*minenc);
  float mx_d = (1.0f - cosmin) / 0.2f;
  float mn_d = (1.0f - cosmax) / 0.2f;
  float middle = (mx_d + mn_d) / 2.0f;
  float amplitude = fmaxf(mx_d - middle + 1e-5f, 1e-5f);
  scal[0] = middle;
  scal[1] = amplitude;
  scal[2] = 1.0f / amplitude;
}

// ---- Sinkhorn sweep: wave-per-row, zero per-row barriers, depth-1 prefetch
// (R9-proven: cva/cvb constant-indexed -> registers, no scratch) ----
#define SROWS 32
#define SRPW  8

__global__ __launch_bounds__(256) void vq_sweep(const float* __restrict__ Cm,
                                                const float* __restrict__ scal,
                                                const double* __restrict__ Rvec,
                                                const double* __restrict__ alpha_p,
                                                double* __restrict__ u_out) {
  int t = threadIdx.x;
  int lane = t & 63, wv = t >> 6;
  int n0 = blockIdx.x * SROWS + wv * SRPW;
  float middle = scal[0], amp = scal[1], rc = scal[2];
  bool hasR = (Rvec != nullptr);
  double Rreg[16];
  double ainv = 0.0;
  if (hasR) {
#pragma unroll
    for (int c = 0; c < 4; ++c)
#pragma unroll
      for (int e = 0; e < 4; ++e) Rreg[c * 4 + e] = Rvec[c * 256 + lane * 4 + e];
    ainv = alpha_p[0] * 32768.0;
  }
  double up[16] = {};
  float4 cva[4], cvb[4];
  {
    const float4* row0 = (const float4*)(Cm + (size_t)n0 * KCB);
#pragma unroll
    for (int c = 0; c < 4; ++c) cva[c] = row0[c * 64 + lane];
  }
#pragma unroll 1
  for (int r = 0; r < SRPW; ++r) {
    int rn = (r < SRPW - 1) ? r + 1 : r;
    const float4* rown = (const float4*)(Cm + (size_t)(n0 + rn) * KCB);
#pragma unroll
    for (int c = 0; c < 4; ++c) cvb[c] = rown[c * 64 + lane];
    double e[16];
#pragma unroll
    for (int c = 0; c < 4; ++c) {
      e[c * 4 + 0] = sweep_E(cva[c].x, middle, amp, rc);
      e[c * 4 + 1] = sweep_E(cva[c].y, middle, amp, rc);
      e[c * 4 + 2] = sweep_E(cva[c].z, middle, amp, rc);
      e[c * 4 + 3] = sweep_E(cva[c].w, middle, amp, rc);
    }
    if (hasR) {
      double s = 0.0;
#pragma unroll
      for (int i = 0; i < 16; ++i) s += e[i] * Rreg[i];
#pragma unroll
      for (int off = 1; off < 64; off <<= 1) s += __shfl_xor(s, off, 64);
      double C = 1.0 / (ainv * s);
#pragma unroll
      for (int i = 0; i < 16; ++i) up[i] += e[i] * C;
    } else {
#pragma unroll
      for (int i = 0; i < 16; ++i) up[i] += e[i];
    }
#pragma unroll
    for (int c = 0; c < 4; ++c) cva[c] = cvb[c];
  }
  __shared__ double su[4][KCB];  // 32 KB
#pragma unroll
  for (int c = 0; c < 4; ++c)
#pragma unroll
    for (int e = 0; e < 4; ++e) su[wv][c * 256 + lane * 4 + e] = up[c * 4 + e];
  __syncthreads();
#pragma unroll
  for (int j = 0; j < 4; ++j) {
    int k = (t + ((blockIdx.x + j) & 3) * 256) & (KCB - 1);
    double v = su[0][k] + su[1][k] + su[2][k] + su[3][k];
    atomic_add_f64(&u_out[k], v);
  }
}

// mode 0: also compute alpha = 1/max(sum u, 1e-5); mode 2: also lnR
__global__ __launch_bounds__(1024) void vq_finalize_u(const double* __restrict__ u,
                                                      double* __restrict__ alpha_p,
                                                      double* __restrict__ R,
                                                      double* __restrict__ lnR,
                                                      int mode) {
  int k = threadIdx.x;
  double uk = u[k];
  __shared__ double red[16];
  __shared__ double s_alpha;
  if (mode == 0) {
    double s = uk;
#pragma unroll
    for (int off = 32; off; off >>= 1) s += __shfl_down(s, off, 64);
    if ((k & 63) == 0) red[k >> 6] = s;
    __syncthreads();
    if (k == 0) {
      double s0 = 0.0;
      for (int w = 0; w < 16; ++w) s0 += red[w];
      double a = 1.0 / fmax(s0, 1e-5);
      s_alpha = a;
      alpha_p[0] = a;
    }
    __syncthreads();
  }
  double alpha = (mode == 0) ? s_alpha : alpha_p[0];
  double r = 1.0 / (alpha * 1024.0 * uk);
  R[k] = r;
  if (mode == 2) lnR[k] = log(r);
}

// ---- final pass: wave-per-row; f32 top-2 argmax with exact-recheck, CE loss
// (R9-proven body: depth-1 prefetch, no scratch) ----
#define FRPW 4
#define MARGIN 0.08f
#define LOG2E 1.44269504088896340736f

__global__ __launch_bounds__(256) void vq_final_pass(const float* __restrict__ Cm,
                                                     const float* __restrict__ x,
                                                     const float* __restrict__ cb,
                                                     const float* __restrict__ xn,
                                                     const float* __restrict__ cn,
                                                     const double* __restrict__ lnR,
                                                     const float* __restrict__ scal,
                                                     double* __restrict__ loss_part,
                                                     float* __restrict__ out_xq,
                                                     float* __restrict__ out_idx) {
  int t = threadIdx.x;
  int lane = t & 63, wv = t >> 6;
  int n0 = blockIdx.x * (4 * FRPW) + wv * FRPW;
  float middle = scal[0], amplitude = scal[1], rc_amp = scal[2];
  float lnRf[16];
  double lnRd[16];
#pragma unroll
  for (int c = 0; c < 4; ++c)
#pragma unroll
    for (int e = 0; e < 4; ++e) {
      double v = lnR[c * 256 + lane * 4 + e];
      lnRd[c * 4 + e] = v;
      lnRf[c * 4 + e] = (float)v;
    }

  double loss_loc = 0.0;
  float4 cva[4], cvb[4];
  {
    const float4* row0 = (const float4*)(Cm + (size_t)n0 * KCB);
#pragma unroll
    for (int c = 0; c < 4; ++c) cva[c] = row0[c * 64 + lane];
  }
#pragma unroll 1
  for (int r = 0; r < FRPW; ++r) {
    int n = n0 + r;
    int rn = (r < FRPW - 1) ? r + 1 : r;
    const float4* rown = (const float4*)(Cm + (size_t)(n0 + rn) * KCB);
#pragma unroll
    for (int c = 0; c < 4; ++c) cvb[c] = rown[c * 64 + lane];

    float lv[16];
    float sv[16];
    float b1 = -3.402823466e38f, b2 = -3.402823466e38f;
    int k1 = 0;
    float lmax = -3.402823466e38f;
#pragma unroll
    for (int c = 0; c < 4; ++c) {
#pragma unroll
      for (int e = 0; e < 4; ++e) {
        float cvv = (e == 0) ? cva[c].x : (e == 1) ? cva[c].y : (e == 2) ? cva[c].z : cva[c].w;
        int k = c * 256 + lane * 4 + e;  // ascending within lane
        float d  = div_mark(1.0f - cvv, 0.2f, 5.0f);
        float dc = div_mark(d - middle, amplitude, rc_amp);
        float s  = fmaf(dc, -200.0f, lnRf[c * 4 + e]);
        sv[c * 4 + e] = s;
        if (s > b1) { b2 = b1; b1 = s; k1 = k; }
        else if (s > b2) b2 = s;
        float l = div_mark(cvv, 0.2f, 5.0f);
        lv[c * 4 + e] = l;
        lmax = fmaxf(lmax, l);
      }
    }
    // butterfly top-2 (tie -> smaller k) + max reduce; all lanes converge
#pragma unroll
    for (int off = 1; off < 64; off <<= 1) {
      float o1 = __shfl_xor(b1, off, 64);
      int ok = __shfl_xor(k1, off, 64);
      float o2 = __shfl_xor(b2, off, 64);
      float om = __shfl_xor(lmax, off, 64);
      float cand2;
      if (o1 > b1 || (o1 == b1 && ok < k1)) { cand2 = fmaxf(b1, o2); b1 = o1; k1 = ok; }
      else cand2 = fmaxf(o1, o2);
      b2 = fmaxf(b2, cand2);
      lmax = fmaxf(lmax, om);
    }
    int bestk = k1;
    if (b1 - b2 < MARGIN) {
      // close call: recheck flagged candidates with exact f32 dot + f64 score
      double pbest = -1.0e308;
      int pk = KCB;
      const float* xr = xn + (size_t)n * DDIM;
      float thr = b1 - MARGIN;
#pragma unroll 1
      for (int i = 0; i < 16; ++i) {
        if (sv[i] >= thr) {
          int k = (i >> 2) * 256 + lane * 4 + (i & 3);
          const float* cr = cn + (size_t)k * DDIM;
          float dot = 0.0f;
          for (int d = 0; d < DDIM; ++d) dot = fmaf(xr[d], cr[d], dot);
          double ps = score_exponent(dot, middle, amplitude) + lnRd[i];
          if (ps > pbest || (ps == pbest && k < pk)) { pbest = ps; pk = k; }
        }
      }
#pragma unroll
      for (int off = 1; off < 64; off <<= 1) {
        double ob = __shfl_xor(pbest, off, 64);
        int ok = __shfl_xor(pk, off, 64);
        if (ob > pbest || (ob == pbest && ok < pk)) { pbest = ob; pk = ok; }
      }
      bestk = pk;
    }
    // sum exp (f32, fused exp2) + extract l[bestk]
    float se = 0.0f;
    float lb = 0.0f;
#pragma unroll
    for (int c = 0; c < 4; ++c) {
#pragma unroll
      for (int e = 0; e < 4; ++e) {
        int k = c * 256 + lane * 4 + e;
        se += hw_exp2((lv[c * 4 + e] - lmax) * LOG2E);
        if (k == bestk) lb = lv[c * 4 + e];
      }
    }
#pragma unroll
    for (int off = 1; off < 64; off <<= 1) {
      se += __shfl_xor(se, off, 64);
      lb += __shfl_xor(lb, off, 64);  // exactly one lane nonzero
    }
    loss_loc += (double)(-(lb - lmax - logf(se)));
    if (lane == 0) out_idx[n] = (float)bestk;
    float2 xv = *(const float2*)&x[(size_t)n * DDIM + lane * 2];
    float2 cbv = *(const float2*)&cb[(size_t)bestk * DDIM + lane * 2];
    float2 o;
    o.x = xv.x + (cbv.x - xv.x);
    o.y = xv.y + (cbv.y - xv.y);
    *(float2*)&out_xq[(size_t)n * DDIM + lane * 2] = o;
#pragma unroll
    for (int c = 0; c < 4; ++c) cva[c] = cvb[c];
  }
  if (lane == 0) atomic_add_f64(&loss_part[(blockIdx.x * 4 + wv) & (KCB - 1)], loss_loc);
}

__global__ __launch_bounds__(1024) void vq_loss_div(const double* __restrict__ lp,
                                                    float* __restrict__ out_loss) {
  int t = threadIdx.x;
  double s = lp[t];
#pragma unroll
  for (int off = 32; off; off >>= 1) s += __shfl_down(s, off, 64);
  __shared__ double red[16];
  if ((t & 63) == 0) red[t >> 6] = s;
  __syncthreads();
  if (t == 0) {
    double tot = 0.0;
    for (int w = 0; w < 16; ++w) tot += red[w];
    out_loss[0] = (float)(tot / 32768.0);
  }
}

// ---------- launch ----------

extern "C" void kernel_launch(void* const* d_in, const int* in_sizes, int n_in,
                              void* d_out, int out_size, void* d_ws, size_t ws_size,
                              hipStream_t stream) {
  const float* x  = (const float*)d_in[0];
  const float* cb = (const float*)d_in[1];
  float* out = (float*)d_out;
  float* out_xq   = out;
  float* out_loss = out + (size_t)NPTS * DDIM;
  float* out_idx  = out + (size_t)NPTS * DDIM + 1;

  // workspace layout (~144.6 MB):
  // [0, 16.5MB): phase 1 = bf16 planes (xh 8M, xl 8M, ch 256K, cl 256K)
  //              phase 2 (post-GEMM) = xn f32 16M, cn f32 512K  (overlay)
  char* w = (char*)d_ws;
  unsigned short* xh = (unsigned short*)w;                         // N*D bf16
  unsigned short* xl = xh + (size_t)NPTS * DDIM;                   // N*D bf16
  unsigned short* ch = xl + (size_t)NPTS * DDIM;                   // K*D bf16
  unsigned short* cl = ch + (size_t)KCB * DDIM;                    // K*D bf16
  float* xn = (float*)w;                                           // N*D f32 (overlay)
  float* cn = xn + (size_t)NPTS * DDIM;                            // K*D f32 (overlay)
  float* cosm = (float*)(w + (size_t)16896 * 1024);                // N*K f32 at +16.5MB
  double* u1  = (double*)(cosm + (size_t)NPTS * KCB);
  double* u2  = u1 + KCB;
  double* u3  = u2 + KCB;
  double* R   = u3 + KCB;
  double* lnR = R + KCB;
  double* loss_part = lnR + KCB;                   // 1024
  double* alpha_p   = loss_part + KCB;
  unsigned* maxenc = (unsigned*)(alpha_p + 1);
  unsigned* minenc = maxenc + 1;
  float* scal = (float*)(minenc + 1);              // middle, amplitude, rc_amp

  vq_init_kernel<<<1, 1024, 0, stream>>>(u1, loss_part, maxenc, minenc);

  // phase 1: split-normalized bf16 planes -> MFMA GEMM (double-buffered async LDS)
  vq_normalize_split<<<NPTS, 128, 0, stream>>>(x, xh, xl);
  vq_normalize_split<<<KCB, 128, 0, stream>>>(cb, ch, cl);
  vq_gemm_mfma<<<dim3(NPTS / 128, KCB / 128), 256, 0, stream>>>(xh, xl, ch, cl, cosm,
                                                                maxenc, minenc);

  // phase 2: f32 normalized copies (overwrite plane region) for the recheck path
  vq_normalize_rows<<<NPTS, 128, 0, stream>>>(x, xn);
  vq_normalize_rows<<<KCB, 128, 0, stream>>>(cb, cn);
  vq_scalarize<<<1, 1, 0, stream>>>(maxenc, minenc, scal);

  // Sinkhorn: u1 -> R1 ; (v1+u2 fused) -> R2 ; (v2+u3 fused) -> R3, lnR3
  vq_sweep<<<NPTS / SROWS, 256, 0, stream>>>(cosm, scal, nullptr, alpha_p, u1);
  vq_finalize_u<<<1, 1024, 0, stream>>>(u1, alpha_p, R, lnR, 0);
  vq_sweep<<<NPTS / SROWS, 256, 0, stream>>>(cosm, scal, R, alpha_p, u2);
  vq_finalize_u<<<1, 1024, 0, stream>>>(u2, alpha_p, R, lnR, 1);
  vq_sweep<<<NPTS / SROWS, 256, 0, stream>>>(cosm, scal, R, alpha_p, u3);
  vq_finalize_u<<<1, 1024, 0, stream>>>(u3, alpha_p, R, lnR, 2);

  vq_final_pass<<<NPTS / (4 * FRPW), 256, 0, stream>>>(cosm, x, cb, xn, cn, lnR, scal,
                                                       loss_part, out_xq, out_idx);
  vq_loss_div<<<1, 1024, 0, stream>>>(loss_part, out_loss);
}